// Round 4
// baseline (1554.085 us; speedup 1.0000x reference)
//
#include <hip/hip_runtime.h>

// ---------------------------------------------------------------------------
// BiLSTM seq2seq + attention + vocab softmax for MI355X (gfx950).
// B=4, T=128, E=512, H=512, D=1024, V=32000.
// Round 4: operand-swapped MFMA (A=Wh, B=h) with colmap c=q*4+r puts ALL FOUR
// gates of one (batch,unit) in one lane's accumulator -> register cell state,
// one barrier/step, no LDS gate transpose. Pipelined double-batch polling.
// Per-WG in-LDS xw strips (bias folded). Attention fused into the dec launch,
// reading a non-recycled tagged bf16 h-history (dec_out buffer eliminated).
// ---------------------------------------------------------------------------

typedef __attribute__((ext_vector_type(8))) short bf16x8;   // 8 bf16 = 4 VGPRs
typedef __attribute__((ext_vector_type(4))) float f32x4;

__device__ __forceinline__ short f2bf(float f) {  // RNE fp32 -> bf16
  unsigned u = __builtin_bit_cast(unsigned, f);
  u += 0x7fffu + ((u >> 16) & 1u);
  return (short)(u >> 16);
}
__device__ __forceinline__ float b2f(short s) {
  unsigned u = ((unsigned)(unsigned short)s) << 16;
  return __builtin_bit_cast(float, u);
}
__device__ __forceinline__ float sigf(float x) { return 1.f / (1.f + __expf(-x)); }
__device__ __forceinline__ float tanhf_fast(float x) {
  x = fminf(fmaxf(x, -15.f), 15.f);
  float e = __expf(2.f * x);
  return (e - 1.f) / (e + 1.f);
}
__device__ __forceinline__ unsigned ld_coh(const unsigned* p) {
  return __hip_atomic_load(p, __ATOMIC_RELAXED, __HIP_MEMORY_SCOPE_AGENT);
}
__device__ __forceinline__ void st_coh(unsigned* p, unsigned v) {
  __hip_atomic_store(p, v, __ATOMIC_RELAXED, __HIP_MEMORY_SCOPE_AGENT);
}

// ---- workspace layout -----------------------------------------------------
#define OFF_HBF   ((size_t)0)                        // enc fwd h pingpong [2][2048] u32
#define OFF_HBB   (OFF_HBF + (size_t)2*2048*4)
#define OFF_HBD   (OFF_HBB + (size_t)2*2048*4)       // dec h pingpong [2][4096] u32
#define OFF_HBH   (OFF_HBD + (size_t)2*4096*4)       // dec h history [128][4][1024] u32
#define OFF_ENCX  (OFF_HBH + (size_t)128*4*1024*4)   // enc_x swz [64][512][8] bf16
#define OFF_DECX  (OFF_ENCX + (size_t)64*512*8*2)
#define OFF_WOS   (OFF_DECX + (size_t)64*512*8*2)    // Wo swz [128][32000][8] bf16
#define OFF_ENCO  (OFF_WOS + (size_t)1024*32000*2)   // enc_out fp32 [4][128][1024]
#define OFF_ENCT  (OFF_ENCO + (size_t)4*128*1024*4)  // enc_out^T fp32 [4][1024][128]
#define OFF_ATTN  (OFF_ENCT + (size_t)4*128*1024*4)  // attn swz [128][512][8] bf16
#define OFF_LOG   (OFF_ATTN + (size_t)128*512*8*2)   // logits bf16 [512][32000]
#define WS_NEED   (OFF_LOG + (size_t)512*32000*2)

// ---- small bodies ---------------------------------------------------------
__device__ __forceinline__ void gather_body(const int* seq, const float* emb,
                                            short* dst, int bx, int by) {
  int m  = by * 64 + (threadIdx.x & 63);
  int e8 = bx * 4 + (threadIdx.x >> 6);
  int id = seq[m];
  const float* src = emb + (size_t)id * 512 + e8 * 8;
  bf16x8 v;
#pragma unroll
  for (int j = 0; j < 8; ++j) v[j] = f2bf(src[j]);
  *(bf16x8*)(dst + ((size_t)e8 * 512 + m) * 8) = v;
}

__device__ __forceinline__ void swz_body(const float* W, short* dst, int N,
                                         int k8, int n) {
  const float* src = W + (size_t)k8 * 8 * N + n;
  bf16x8 v;
#pragma unroll
  for (int j = 0; j < 8; ++j) v[j] = f2bf(src[(size_t)j * N]);
  *(bf16x8*)(dst + ((size_t)k8 * N + n) * 8) = v;
}

// ---- prep: embedding gathers -> swizzled bf16 A matrices ------------------
__global__ __launch_bounds__(256) void prep(const int* __restrict__ iseq,
                                            const int* __restrict__ oseq,
                                            const float* __restrict__ enc_emb,
                                            const float* __restrict__ dec_emb,
                                            short* encx, short* decx) {
  int bid = blockIdx.x;
  if (bid < 128) gather_body(iseq, enc_emb, encx, bid & 15, bid >> 4);
  else { int s = bid - 128; gather_body(oseq, dec_emb, decx, s & 15, s >> 4); }
}

// ---- encoder LSTM (blocks 0..63) + Wo swizzle (64..16063) -----------------
__global__ __launch_bounds__(256, 1) void lstm_enc_fused(
    const float* __restrict__ Wh_f, const float* __restrict__ Wh_b,
    const float* __restrict__ Wx_f, const float* __restrict__ Wx_b,
    const float* __restrict__ b_f, const float* __restrict__ b_b,
    const short* __restrict__ encx,
    unsigned* hb_f, unsigned* hb_b, float* enc_out, float* encT,
    const float* __restrict__ Wo, short* wo_s) {
  const int bid = blockIdx.x, tid = threadIdx.x;
  if (bid >= 64) {                       // Wo swizzle role
    int sb = bid - 64;
    int k8 = sb / 125, nb = sb - k8 * 125;
    swz_body(Wo, wo_s, 32000, k8, nb * 256 + tid);
    return;
  }
  // ---------------- LSTM role ----------------
  __shared__ float xws[512][16];         // xw strip (+bias), [m=b*128+t][c]
  __shared__ short hs[4][528];           // staged h_t, [b][k]; 528: 2-way banks
  const int dir = bid >> 5, u0 = (bid & 31) * 16;
  const int w = tid >> 6, lane = tid & 63, q = lane >> 4, l15 = lane & 15;
  const int bq = l15 & 3;
  const int unit = u0 + w * 4 + q;       // this lane's unit (gate lanes l15<4)
  unsigned* hb = dir ? hb_b : hb_f;

  // publish h0 = 0 (tag 1, parity 0) early so peers' first polls can pass
  if (l15 < 4) st_coh(hb + l15 * 512 + unit, 1u << 16);

  // colmap: C row m=c: gate=(c&3), uu=(c>>2); this lane's A-row = l15
  const int colA = (l15 & 3) * 512 + u0 + w * 4 + (l15 >> 2);
  const float* Wx   = dir ? Wx_b : Wx_f;
  const float* bias = dir ? b_b : b_f;
  const float bcol = bias[colA];

  // in-WG xw strip GEMM: xws[m][c] = (x @ Wx)[m][colA(c)] + bias
  {
    bf16x8 bfr[16];
#pragma unroll
    for (int ks = 0; ks < 16; ++ks) {
      bf16x8 v;
#pragma unroll
      for (int jj = 0; jj < 8; ++jj)
        v[jj] = f2bf(Wx[(size_t)(ks * 32 + q * 8 + jj) * 2048 + colA]);
      bfr[ks] = v;
    }
    for (int mt = 0; mt < 32; ++mt) {
      f32x4 a0 = {0.f,0.f,0.f,0.f}, a1 = a0;
#pragma unroll
      for (int ks = 0; ks < 16; ks += 2) {
        bf16x8 f0 = *(const bf16x8*)(encx + ((size_t)(ks*4 + q) * 512 + mt*16 + l15) * 8);
        bf16x8 f1 = *(const bf16x8*)(encx + ((size_t)((ks+1)*4 + q) * 512 + mt*16 + l15) * 8);
        a0 = __builtin_amdgcn_mfma_f32_16x16x32_bf16(f0, bfr[ks], a0, 0, 0, 0);
        a1 = __builtin_amdgcn_mfma_f32_16x16x32_bf16(f1, bfr[ks+1], a1, 0, 0, 0);
      }
#pragma unroll
      for (int r = 0; r < 4; ++r) xws[mt*16 + q*4 + r][l15] = a0[r] + a1[r] + bcol;
    }
  }
  // recurrent weights as A-operand fragments: A[m=l15][k] = Wh[k][colA]
  const float* Wh = dir ? Wh_b : Wh_f;
  bf16x8 wfrag[16];
#pragma unroll
  for (int ks = 0; ks < 16; ++ks) {
    bf16x8 v;
#pragma unroll
    for (int jj = 0; jj < 8; ++jj)
      v[jj] = f2bf(Wh[(size_t)(ks * 32 + q * 8 + jj) * 2048 + colA]);
    wfrag[ks] = v;
  }
  __syncthreads();                       // xws ready
  float creg = 0.f;                      // cell state (b=l15, unit) in-register
  f32x4 xwv = *(const f32x4*)&xws[bq * 128 + (dir ? 127 : 0)][q * 4];

#pragma unroll 1
  for (int t = 0; t < 128; ++t) {
    const unsigned exp_ = (unsigned)(t + 1);
    const unsigned* src = hb + (t & 1) * 2048;
    unsigned pa[8], pb[8];
#pragma unroll
    for (int j = 0; j < 8; ++j) pa[j] = ld_coh(src + j * 256 + tid);
#pragma unroll
    for (int j = 0; j < 8; ++j) pb[j] = ld_coh(src + j * 256 + tid);
    int guard = 0;
    for (;;) {                           // two batches in flight -> lag ~1 RT
      bool ok = true;
#pragma unroll
      for (int j = 0; j < 8; ++j) ok &= (pa[j] >> 16) == exp_;
      if (ok || ++guard > (1 << 16)) break;
#pragma unroll
      for (int j = 0; j < 8; ++j) pa[j] = pb[j];
#pragma unroll
      for (int j = 0; j < 8; ++j) pb[j] = ld_coh(src + j * 256 + tid);
    }
#pragma unroll
    for (int j = 0; j < 8; ++j) {
      int idx = j * 256 + tid;
      hs[idx >> 9][idx & 511] = (short)(pa[j] & 0xffffu);
    }
    __syncthreads();                     // the ONLY barrier per step

    f32x4 a0 = {0.f,0.f,0.f,0.f}, a1 = a0, a2 = a0, a3 = a0;
    const short* hrow = hs[bq];
#pragma unroll
    for (int ks = 0; ks < 16; ks += 4) {
      bf16x8 h0 = *(const bf16x8*)(hrow + ks * 32 + q * 8);
      bf16x8 h1 = *(const bf16x8*)(hrow + (ks+1) * 32 + q * 8);
      bf16x8 h2 = *(const bf16x8*)(hrow + (ks+2) * 32 + q * 8);
      bf16x8 h3 = *(const bf16x8*)(hrow + (ks+3) * 32 + q * 8);
      a0 = __builtin_amdgcn_mfma_f32_16x16x32_bf16(wfrag[ks],   h0, a0, 0, 0, 0);
      a1 = __builtin_amdgcn_mfma_f32_16x16x32_bf16(wfrag[ks+1], h1, a1, 0, 0, 0);
      a2 = __builtin_amdgcn_mfma_f32_16x16x32_bf16(wfrag[ks+2], h2, a2, 0, 0, 0);
      a3 = __builtin_amdgcn_mfma_f32_16x16x32_bf16(wfrag[ks+3], h3, a3, 0, 0, 0);
    }
    const int tx = dir ? (127 - t) : t;
    if (l15 < 4) {                       // gate lanes: all 4 gates in-register
      const int b = l15;
      float zi = a0[0] + a1[0] + a2[0] + a3[0] + xwv[0];
      float zf = a0[1] + a1[1] + a2[1] + a3[1] + xwv[1];
      float zg = a0[2] + a1[2] + a2[2] + a3[2] + xwv[2];
      float zo = a0[3] + a1[3] + a2[3] + a3[3] + xwv[3];
      float cst = sigf(zf) * creg + sigf(zi) * tanhf_fast(zg);
      creg = cst;
      float h = sigf(zo) * tanhf_fast(cst);
      if (t < 127)
        st_coh(hb + ((t + 1) & 1) * 2048 + b * 512 + unit,
               ((unsigned)(t + 2) << 16) | (unsigned short)f2bf(h));
      const int d = dir * 512 + unit;
      enc_out[((size_t)(b * 128 + tx)) * 1024 + d] = h;
      encT[((size_t)(b * 1024 + d)) * 128 + tx] = h;
    }
    if (t < 127)
      xwv = *(const f32x4*)&xws[bq * 128 + (dir ? 126 - t : t + 1)][q * 4];
    // no second barrier: staging t+1 is gated by poll(h_{t+1}) which implies
    // every wave (incl. our own WG's) finished its step-t MFMA reads of hs.
  }
}

// ---- decoder LSTM (blocks 0..63) + fused attention (64..575) --------------
struct DecL { float xws[512][16]; short hs[4][1056]; };
struct DecA { float dec_s[1024]; float scl[1024]; float red[256]; float wts[128]; float sred[2]; };

__global__ __launch_bounds__(256, 1) void lstm_dec_fused(
    const float* __restrict__ Wh_d, const float* __restrict__ Wx_d,
    const float* __restrict__ b_d, const short* __restrict__ decx,
    const float* __restrict__ enc_out, const float* __restrict__ encT,
    const float* __restrict__ scale,
    unsigned* hb, unsigned* hbh, short* attn_swz) {
  const int bid = blockIdx.x, tid = threadIdx.x;
  __shared__ union { DecL l; DecA a; } sh;

  if (bid >= 64) {
    // ------------- attention role: one block per (b,t) -------------
    const int m = bid - 64, b = m >> 7, t = m & 127;
    const unsigned exp_ = (unsigned)(t + 2);
    const unsigned* src = hbh + ((size_t)t * 4 + b) * 1024;
    float* dec_s = sh.a.dec_s; float* scl_s = sh.a.scl;
    float* red = sh.a.red; float* wts = sh.a.wts; float* sred = sh.a.sred;
#pragma unroll
    for (int kk = 0; kk < 4; ++kk) {
      int d = tid + kk * 256;
      unsigned v = ld_coh(src + d);
      int g = 0;
      while ((v >> 16) != exp_) {
        __builtin_amdgcn_s_sleep(64);
        v = ld_coh(src + d);
        if (++g > (1 << 13)) break;
      }
      dec_s[d] = b2f((short)(v & 0xffffu));
      scl_s[d] = scale[d];
    }
    __syncthreads();
    const int s = tid & 127, half = tid >> 7;
    float sc = 0.f;
    const float* ep = encT + (size_t)b * 1024 * 128 + s;
    for (int d = half * 512; d < half * 512 + 512; ++d)
      sc += tanhf_fast(dec_s[d] + ep[(size_t)d * 128]) * scl_s[d];
    red[tid] = sc;
    __syncthreads();
    float v = 0.f;
    if (tid < 128) { v = red[tid] + red[tid + 128]; wts[tid] = v; }
    __syncthreads();
    if (tid < 64) {
      float mx = fmaxf(wts[tid], wts[tid + 64]);
      for (int off = 32; off; off >>= 1) mx = fmaxf(mx, __shfl_down(mx, off));
      if (tid == 0) sred[0] = mx;
    }
    __syncthreads();
    const float MX = sred[0];
    if (tid < 128) { v = __expf(v - MX); wts[tid] = v; }
    __syncthreads();
    if (tid < 64) {
      float sm = wts[tid] + wts[tid + 64];
      for (int off = 32; off; off >>= 1) sm += __shfl_down(sm, off);
      if (tid == 0) sred[1] = sm;
    }
    __syncthreads();
    const float inv = 1.f / sred[1];
    if (tid < 128) wts[tid] = v * inv;
    __syncthreads();
#pragma unroll
    for (int kk = 0; kk < 4; ++kk) {
      int d = tid + kk * 256;
      float a = 0.f;
      for (int ss = 0; ss < 128; ++ss)
        a += wts[ss] * enc_out[((size_t)(b * 128 + ss)) * 1024 + d];
      attn_swz[((size_t)(d >> 3) * 512 + m) * 8 + (d & 7)] = f2bf(a);
    }
    return;
  }
  // ---------------- LSTM role ----------------
  const int u0 = bid * 16;
  const int w = tid >> 6, lane = tid & 63, q = lane >> 4, l15 = lane & 15;
  const int bq = l15 & 3;
  const int unit = u0 + w * 4 + q;

  // publish h0 = enc_out[:,127,:] (tag 1, parity 0) early
  if (l15 < 4)
    st_coh(hb + l15 * 1024 + unit,
           (1u << 16) |
           (unsigned short)f2bf(enc_out[((size_t)(l15 * 128 + 127)) * 1024 + unit]));

  const int colA = (l15 & 3) * 1024 + u0 + w * 4 + (l15 >> 2);
  const float bcol = b_d[colA];
  // in-WG xw strip GEMM (K=512)
  {
    bf16x8 bfr[16];
#pragma unroll
    for (int ks = 0; ks < 16; ++ks) {
      bf16x8 v;
#pragma unroll
      for (int jj = 0; jj < 8; ++jj)
        v[jj] = f2bf(Wx_d[(size_t)(ks * 32 + q * 8 + jj) * 4096 + colA]);
      bfr[ks] = v;
    }
    for (int mt = 0; mt < 32; ++mt) {
      f32x4 a0 = {0.f,0.f,0.f,0.f}, a1 = a0;
#pragma unroll
      for (int ks = 0; ks < 16; ks += 2) {
        bf16x8 f0 = *(const bf16x8*)(decx + ((size_t)(ks*4 + q) * 512 + mt*16 + l15) * 8);
        bf16x8 f1 = *(const bf16x8*)(decx + ((size_t)((ks+1)*4 + q) * 512 + mt*16 + l15) * 8);
        a0 = __builtin_amdgcn_mfma_f32_16x16x32_bf16(f0, bfr[ks], a0, 0, 0, 0);
        a1 = __builtin_amdgcn_mfma_f32_16x16x32_bf16(f1, bfr[ks+1], a1, 0, 0, 0);
      }
#pragma unroll
      for (int r = 0; r < 4; ++r) sh.l.xws[mt*16 + q*4 + r][l15] = a0[r] + a1[r] + bcol;
    }
  }
  bf16x8 wfrag[32];
#pragma unroll
  for (int ks = 0; ks < 32; ++ks) {
    bf16x8 v;
#pragma unroll
    for (int jj = 0; jj < 8; ++jj)
      v[jj] = f2bf(Wh_d[(size_t)(ks * 32 + q * 8 + jj) * 4096 + colA]);
    wfrag[ks] = v;
  }
  __syncthreads();
  float creg = 0.f;
  f32x4 xwv = *(const f32x4*)&sh.l.xws[bq * 128][q * 4];

#pragma unroll 1
  for (int t = 0; t < 128; ++t) {
    const unsigned exp_ = (unsigned)(t + 1);
    const unsigned* src = hb + (t & 1) * 4096;
    unsigned pa[16], pb[16];
#pragma unroll
    for (int j = 0; j < 16; ++j) pa[j] = ld_coh(src + j * 256 + tid);
#pragma unroll
    for (int j = 0; j < 16; ++j) pb[j] = ld_coh(src + j * 256 + tid);
    int guard = 0;
    for (;;) {
      bool ok = true;
#pragma unroll
      for (int j = 0; j < 16; ++j) ok &= (pa[j] >> 16) == exp_;
      if (ok || ++guard > (1 << 16)) break;
#pragma unroll
      for (int j = 0; j < 16; ++j) pa[j] = pb[j];
#pragma unroll
      for (int j = 0; j < 16; ++j) pb[j] = ld_coh(src + j * 256 + tid);
    }
#pragma unroll
    for (int j = 0; j < 16; ++j) {
      int idx = j * 256 + tid;
      sh.l.hs[idx >> 10][idx & 1023] = (short)(pa[j] & 0xffffu);
    }
    __syncthreads();

    f32x4 a0 = {0.f,0.f,0.f,0.f}, a1 = a0, a2 = a0, a3 = a0;
    const short* hrow = sh.l.hs[bq];
#pragma unroll
    for (int ks = 0; ks < 32; ks += 4) {
      bf16x8 h0 = *(const bf16x8*)(hrow + ks * 32 + q * 8);
      bf16x8 h1 = *(const bf16x8*)(hrow + (ks+1) * 32 + q * 8);
      bf16x8 h2 = *(const bf16x8*)(hrow + (ks+2) * 32 + q * 8);
      bf16x8 h3 = *(const bf16x8*)(hrow + (ks+3) * 32 + q * 8);
      a0 = __builtin_amdgcn_mfma_f32_16x16x32_bf16(wfrag[ks],   h0, a0, 0, 0, 0);
      a1 = __builtin_amdgcn_mfma_f32_16x16x32_bf16(wfrag[ks+1], h1, a1, 0, 0, 0);
      a2 = __builtin_amdgcn_mfma_f32_16x16x32_bf16(wfrag[ks+2], h2, a2, 0, 0, 0);
      a3 = __builtin_amdgcn_mfma_f32_16x16x32_bf16(wfrag[ks+3], h3, a3, 0, 0, 0);
    }
    if (l15 < 4) {
      const int b = l15;
      float zi = a0[0] + a1[0] + a2[0] + a3[0] + xwv[0];
      float zf = a0[1] + a1[1] + a2[1] + a3[1] + xwv[1];
      float zg = a0[2] + a1[2] + a2[2] + a3[2] + xwv[2];
      float zo = a0[3] + a1[3] + a2[3] + a3[3] + xwv[3];
      float cst = sigf(zf) * creg + sigf(zi) * tanhf_fast(zg);
      creg = cst;
      float h = sigf(zo) * tanhf_fast(cst);
      unsigned word = ((unsigned)(t + 2) << 16) | (unsigned short)f2bf(h);
      if (t < 127) st_coh(hb + ((t + 1) & 1) * 4096 + b * 1024 + unit, word);
      st_coh(hbh + ((size_t)t * 4 + b) * 1024 + unit, word);   // history for attn
    }
    if (t < 127) xwv = *(const f32x4*)&sh.l.xws[bq * 128 + t + 1][q * 4];
  }
}

// ---- logits = attn @ Wo (LDS-free swizzled GEMM, bf16 out) ----------------
__global__ __launch_bounds__(256) void gemm_wo(const short* __restrict__ A,
                                               const short* __restrict__ B,
                                               short* __restrict__ Cb) {
  const int wv = threadIdx.x >> 6, lane = threadIdx.x & 63;
  const int q = lane >> 4, l15 = lane & 15;
  const int m0 = blockIdx.y * 128 + (wv >> 1) * 64;
  const int n0 = blockIdx.x * 128 + (wv & 1) * 64;
  const int M = 512, N = 32000;
  f32x4 acc[4][4];
#pragma unroll
  for (int i = 0; i < 4; ++i)
#pragma unroll
    for (int j = 0; j < 4; ++j) acc[i][j] = (f32x4){0.f, 0.f, 0.f, 0.f};
  for (int ks = 0; ks < 32; ++ks) {
    const size_t k8 = (size_t)(ks * 4 + q);
    const short* Ap = A + (k8 * M + m0 + l15) * 8;
    const short* Bp = B + (k8 * N + n0 + l15) * 8;
    bf16x8 av[4], bv[4];
#pragma unroll
    for (int i = 0; i < 4; ++i) av[i] = *(const bf16x8*)(Ap + i * 128);
#pragma unroll
    for (int j = 0; j < 4; ++j) bv[j] = *(const bf16x8*)(Bp + j * 128);
#pragma unroll
    for (int i = 0; i < 4; ++i)
#pragma unroll
      for (int j = 0; j < 4; ++j)
        acc[i][j] = __builtin_amdgcn_mfma_f32_16x16x32_bf16(av[i], bv[j], acc[i][j], 0, 0, 0);
  }
#pragma unroll
  for (int i = 0; i < 4; ++i)
#pragma unroll
    for (int j = 0; j < 4; ++j)
#pragma unroll
      for (int r = 0; r < 4; ++r)
        Cb[(size_t)(m0 + i * 16 + q * 4 + r) * N + (n0 + j * 16 + l15)] = f2bf(acc[i][j][r]);
}

// ---- row softmax over 32000 vocab, bf16 logits + bias -> fp32 probs -------
__global__ __launch_bounds__(256) void softmax_out(const short* __restrict__ logits,
                                                   const float* __restrict__ bo,
                                                   float* __restrict__ out) {
  const int m = blockIdx.x, tid = threadIdx.x;
  __shared__ float red[256];
  const short* lp = logits + (size_t)m * 32000;
  float mx = -1e30f;
  for (int n = tid; n < 32000; n += 256) mx = fmaxf(mx, b2f(lp[n]) + bo[n]);
  red[tid] = mx;
  __syncthreads();
  for (int s2 = 128; s2 > 0; s2 >>= 1) {
    if (tid < s2) red[tid] = fmaxf(red[tid], red[tid + s2]);
    __syncthreads();
  }
  const float M = red[0];
  __syncthreads();
  float sm = 0.f;
  for (int n = tid; n < 32000; n += 256) sm += __expf(b2f(lp[n]) + bo[n] - M);
  red[tid] = sm;
  __syncthreads();
  for (int s2 = 128; s2 > 0; s2 >>= 1) {
    if (tid < s2) red[tid] += red[tid + s2];
    __syncthreads();
  }
  const float inv = 1.f / red[0];
  for (int n = tid; n < 32000; n += 256)
    out[(size_t)m * 32000 + n] = __expf(b2f(lp[n]) + bo[n] - M) * inv;
}

// ---------------------------------------------------------------------------
extern "C" void kernel_launch(void* const* d_in, const int* in_sizes, int n_in,
                              void* d_out, int out_size, void* d_ws, size_t ws_size,
                              hipStream_t stream) {
  (void)in_sizes; (void)n_in; (void)out_size;
  if (ws_size < WS_NEED) return;

  const int*   input_seq  = (const int*)d_in[0];
  const int*   output_seq = (const int*)d_in[1];
  const float* enc_emb    = (const float*)d_in[2];
  const float* dec_emb    = (const float*)d_in[3];
  const float* Wx_f = (const float*)d_in[4];
  const float* Wh_f = (const float*)d_in[5];
  const float* b_f  = (const float*)d_in[6];
  const float* Wx_b = (const float*)d_in[7];
  const float* Wh_b = (const float*)d_in[8];
  const float* b_b  = (const float*)d_in[9];
  const float* Wx_d = (const float*)d_in[10];
  const float* Wh_d = (const float*)d_in[11];
  const float* b_d  = (const float*)d_in[12];
  const float* attn_scale = (const float*)d_in[13];
  const float* Wo   = (const float*)d_in[14];
  const float* bo   = (const float*)d_in[15];
  float* out = (float*)d_out;

  char* ws = (char*)d_ws;
  unsigned* hbf   = (unsigned*)(ws + OFF_HBF);
  unsigned* hbb   = (unsigned*)(ws + OFF_HBB);
  unsigned* hbd   = (unsigned*)(ws + OFF_HBD);
  unsigned* hbh   = (unsigned*)(ws + OFF_HBH);
  short* encx     = (short*)(ws + OFF_ENCX);
  short* decx     = (short*)(ws + OFF_DECX);
  short* wo_s     = (short*)(ws + OFF_WOS);
  float* enc_out  = (float*)(ws + OFF_ENCO);
  float* encT     = (float*)(ws + OFF_ENCT);
  short* attn_s   = (short*)(ws + OFF_ATTN);
  short* logits   = (short*)(ws + OFF_LOG);

  // No memset: 0xAA poison yields tag 0xAAAA which never matches a valid tag.

  prep<<<256, 256, 0, stream>>>(input_seq, output_seq, enc_emb, dec_emb, encx, decx);
  lstm_enc_fused<<<64 + 16000, 256, 0, stream>>>(
      Wh_f, Wh_b, Wx_f, Wx_b, b_f, b_b, encx, hbf, hbb, enc_out, encT, Wo, wo_s);
  lstm_dec_fused<<<64 + 512, 256, 0, stream>>>(
      Wh_d, Wx_d, b_d, decx, enc_out, encT, attn_scale, hbd, hbh, attn_s);
  gemm_wo<<<dim3(250, 4), 256, 0, stream>>>(attn_s, wo_s, logits);
  softmax_out<<<512, 256, 0, stream>>>(logits, bo, out);
}

// Round 5
// 1386.873 us; speedup vs baseline: 1.1206x; 1.1206x over previous
//
#include <hip/hip_runtime.h>

// ---------------------------------------------------------------------------
// BiLSTM seq2seq + attention + vocab softmax for MI355X (gfx950).
// B=4, T=128, E=512, H=512, D=1024, V=32000.
// Round 5: ONE mega-kernel runs enc LSTM (blocks 0..63), dec LSTM (64..127),
// and Wo swizzle (128..16127). Dec preamble (Wx_d/Wh_d frag loads + in-LDS xw
// strip GEMM) overlaps the enc phase; enc publishes dec's h0 (tag 1) straight
// into the dec ping-pong buffer. Attention is standalone again (r4's fused
// attention spun on coherent loads next to the LSTM and cost +400 us).
// Poll loops back off with s_sleep to keep the MALL path clear.
// ---------------------------------------------------------------------------

typedef __attribute__((ext_vector_type(8))) short bf16x8;   // 8 bf16 = 4 VGPRs
typedef __attribute__((ext_vector_type(4))) float f32x4;

__device__ __forceinline__ short f2bf(float f) {  // RNE fp32 -> bf16
  unsigned u = __builtin_bit_cast(unsigned, f);
  u += 0x7fffu + ((u >> 16) & 1u);
  return (short)(u >> 16);
}
__device__ __forceinline__ float b2f(short s) {
  unsigned u = ((unsigned)(unsigned short)s) << 16;
  return __builtin_bit_cast(float, u);
}
__device__ __forceinline__ float sigf(float x) { return 1.f / (1.f + __expf(-x)); }
__device__ __forceinline__ float tanhf_fast(float x) {
  x = fminf(fmaxf(x, -15.f), 15.f);
  float e = __expf(2.f * x);
  return (e - 1.f) / (e + 1.f);
}
__device__ __forceinline__ unsigned ld_coh(const unsigned* p) {
  return __hip_atomic_load(p, __ATOMIC_RELAXED, __HIP_MEMORY_SCOPE_AGENT);
}
__device__ __forceinline__ void st_coh(unsigned* p, unsigned v) {
  __hip_atomic_store(p, v, __ATOMIC_RELAXED, __HIP_MEMORY_SCOPE_AGENT);
}

// ---- workspace layout -----------------------------------------------------
#define OFF_HBF   ((size_t)0)                        // enc fwd h pingpong [2][2048] u32
#define OFF_HBB   (OFF_HBF + (size_t)2*2048*4)
#define OFF_HBD   (OFF_HBB + (size_t)2*2048*4)       // dec h pingpong [2][4096] u32
#define OFF_DECO  (OFF_HBD + (size_t)2*4096*4)       // dec_out fp32 [4][128][1024]
#define OFF_ENCX  (OFF_DECO + (size_t)4*128*1024*4)  // enc_x swz [64][512][8] bf16
#define OFF_DECX  (OFF_ENCX + (size_t)64*512*8*2)
#define OFF_WOS   (OFF_DECX + (size_t)64*512*8*2)    // Wo swz [128][32000][8] bf16
#define OFF_ENCO  (OFF_WOS + (size_t)1024*32000*2)   // enc_out fp32 [4][128][1024]
#define OFF_ENCT  (OFF_ENCO + (size_t)4*128*1024*4)  // enc_out^T fp32 [4][1024][128]
#define OFF_ATTN  (OFF_ENCT + (size_t)4*128*1024*4)  // attn swz [128][512][8] bf16
#define OFF_LOG   (OFF_ATTN + (size_t)128*512*8*2)   // logits bf16 [512][32000]
#define WS_NEED   (OFF_LOG + (size_t)512*32000*2)

// ---- small bodies ---------------------------------------------------------
__device__ __forceinline__ void gather_body(const int* seq, const float* emb,
                                            short* dst, int bx, int by) {
  int m  = by * 64 + (threadIdx.x & 63);
  int e8 = bx * 4 + (threadIdx.x >> 6);
  int id = seq[m];
  const float* src = emb + (size_t)id * 512 + e8 * 8;
  bf16x8 v;
#pragma unroll
  for (int j = 0; j < 8; ++j) v[j] = f2bf(src[j]);
  *(bf16x8*)(dst + ((size_t)e8 * 512 + m) * 8) = v;
}

__device__ __forceinline__ void swz_body(const float* W, short* dst, int N,
                                         int k8, int n) {
  const float* src = W + (size_t)k8 * 8 * N + n;
  bf16x8 v;
#pragma unroll
  for (int j = 0; j < 8; ++j) v[j] = f2bf(src[(size_t)j * N]);
  *(bf16x8*)(dst + ((size_t)k8 * N + n) * 8) = v;
}

// ---- prep: embedding gathers -> swizzled bf16 A matrices ------------------
__global__ __launch_bounds__(256) void prep(const int* __restrict__ iseq,
                                            const int* __restrict__ oseq,
                                            const float* __restrict__ enc_emb,
                                            const float* __restrict__ dec_emb,
                                            short* encx, short* decx) {
  int bid = blockIdx.x;
  if (bid < 128) gather_body(iseq, enc_emb, encx, bid & 15, bid >> 4);
  else { int s = bid - 128; gather_body(oseq, dec_emb, decx, s & 15, s >> 4); }
}

// ---- mega: enc LSTM (0..63) + dec LSTM (64..127) + Wo swizzle (128..) -----
struct EncS { float xws[512][16]; short hs[4][528]; };
struct DecS { float xws[512][16]; short hs[4][1056]; };

__global__ __launch_bounds__(256, 1) void lstm_mega(
    const float* __restrict__ Wh_f, const float* __restrict__ Wh_b,
    const float* __restrict__ Wx_f, const float* __restrict__ Wx_b,
    const float* __restrict__ b_f, const float* __restrict__ b_b,
    const float* __restrict__ Wh_d, const float* __restrict__ Wx_d,
    const float* __restrict__ b_d,
    const short* __restrict__ encx, const short* __restrict__ decx,
    unsigned* hb_f, unsigned* hb_b, unsigned* hb_d,
    float* enc_out, float* encT, float* dec_out,
    const float* __restrict__ Wo, short* wo_s) {
  const int bid = blockIdx.x, tid = threadIdx.x;
  __shared__ union { EncS e; DecS d; } sh;

  if (bid >= 128) {                      // ---- Wo swizzle role ----
    int sb = bid - 128;
    int k8 = sb / 125, nb = sb - k8 * 125;
    swz_body(Wo, wo_s, 32000, k8, nb * 256 + tid);
    return;
  }

  const int w = tid >> 6, lane = tid & 63, q = lane >> 4, l15 = lane & 15;
  const int bq = l15 & 3;

  if (bid >= 64) {
    // ================= decoder LSTM role =================
    const int u0 = (bid - 64) * 16;
    const int unit = u0 + w * 4 + q;
    const int colA = (l15 & 3) * 1024 + u0 + w * 4 + (l15 >> 2);
    const float bcol = b_d[colA];
    // in-WG xw strip GEMM (overlaps the encoder phase on other CUs)
    {
      bf16x8 bfr[16];
#pragma unroll
      for (int ks = 0; ks < 16; ++ks) {
        bf16x8 v;
#pragma unroll
        for (int jj = 0; jj < 8; ++jj)
          v[jj] = f2bf(Wx_d[(size_t)(ks * 32 + q * 8 + jj) * 4096 + colA]);
        bfr[ks] = v;
      }
      for (int mt = 0; mt < 32; ++mt) {
        f32x4 a0 = {0.f,0.f,0.f,0.f}, a1 = a0;
#pragma unroll
        for (int ks = 0; ks < 16; ks += 2) {
          bf16x8 f0 = *(const bf16x8*)(decx + ((size_t)(ks*4 + q) * 512 + mt*16 + l15) * 8);
          bf16x8 f1 = *(const bf16x8*)(decx + ((size_t)((ks+1)*4 + q) * 512 + mt*16 + l15) * 8);
          a0 = __builtin_amdgcn_mfma_f32_16x16x32_bf16(f0, bfr[ks], a0, 0, 0, 0);
          a1 = __builtin_amdgcn_mfma_f32_16x16x32_bf16(f1, bfr[ks+1], a1, 0, 0, 0);
        }
#pragma unroll
        for (int r = 0; r < 4; ++r) sh.d.xws[mt*16 + q*4 + r][l15] = a0[r] + a1[r] + bcol;
      }
    }
    bf16x8 wfrag[32];
#pragma unroll
    for (int ks = 0; ks < 32; ++ks) {
      bf16x8 v;
#pragma unroll
      for (int jj = 0; jj < 8; ++jj)
        v[jj] = f2bf(Wh_d[(size_t)(ks * 32 + q * 8 + jj) * 4096 + colA]);
      wfrag[ks] = v;
    }
    __syncthreads();
    float creg = 0.f;
    f32x4 xwv = *(const f32x4*)&sh.d.xws[bq * 128][q * 4];

#pragma unroll 1
    for (int t = 0; t < 128; ++t) {
      const unsigned exp_ = (unsigned)(t + 1);
      const unsigned* src = hb_d + (t & 1) * 4096;
      unsigned pa[16], pb[16];
#pragma unroll
      for (int j = 0; j < 16; ++j) pa[j] = ld_coh(src + j * 256 + tid);
#pragma unroll
      for (int j = 0; j < 16; ++j) pb[j] = ld_coh(src + j * 256 + tid);
      int g = 0;
      for (;;) {
        bool ok = true;
#pragma unroll
        for (int j = 0; j < 16; ++j) ok &= (pa[j] >> 16) == exp_;
        if (ok || g > (1 << 20)) break;
        if (g > 256) __builtin_amdgcn_s_sleep(32);   // t=0: waiting out encoder
        else         __builtin_amdgcn_s_sleep(1);
#pragma unroll
        for (int j = 0; j < 16; ++j) pa[j] = pb[j];
#pragma unroll
        for (int j = 0; j < 16; ++j) pb[j] = ld_coh(src + j * 256 + tid);
        ++g;
      }
#pragma unroll
      for (int j = 0; j < 16; ++j) {
        int idx = j * 256 + tid;
        sh.d.hs[idx >> 10][idx & 1023] = (short)(pa[j] & 0xffffu);
      }
      __syncthreads();                   // the only barrier per step

      f32x4 a0 = {0.f,0.f,0.f,0.f}, a1 = a0, a2 = a0, a3 = a0;
      const short* hrow = sh.d.hs[bq];
#pragma unroll
      for (int ks = 0; ks < 32; ks += 4) {
        bf16x8 h0 = *(const bf16x8*)(hrow + ks * 32 + q * 8);
        bf16x8 h1 = *(const bf16x8*)(hrow + (ks+1) * 32 + q * 8);
        bf16x8 h2 = *(const bf16x8*)(hrow + (ks+2) * 32 + q * 8);
        bf16x8 h3 = *(const bf16x8*)(hrow + (ks+3) * 32 + q * 8);
        a0 = __builtin_amdgcn_mfma_f32_16x16x32_bf16(wfrag[ks],   h0, a0, 0, 0, 0);
        a1 = __builtin_amdgcn_mfma_f32_16x16x32_bf16(wfrag[ks+1], h1, a1, 0, 0, 0);
        a2 = __builtin_amdgcn_mfma_f32_16x16x32_bf16(wfrag[ks+2], h2, a2, 0, 0, 0);
        a3 = __builtin_amdgcn_mfma_f32_16x16x32_bf16(wfrag[ks+3], h3, a3, 0, 0, 0);
      }
      if (l15 < 4) {                     // all 4 gates of (b=l15, unit) here
        const int b = l15;
        float zi = a0[0] + a1[0] + a2[0] + a3[0] + xwv[0];
        float zf = a0[1] + a1[1] + a2[1] + a3[1] + xwv[1];
        float zg = a0[2] + a1[2] + a2[2] + a3[2] + xwv[2];
        float zo = a0[3] + a1[3] + a2[3] + a3[3] + xwv[3];
        float cst = sigf(zf) * creg + sigf(zi) * tanhf_fast(zg);
        creg = cst;
        float h = sigf(zo) * tanhf_fast(cst);
        if (t < 127)
          st_coh(hb_d + ((t + 1) & 1) * 4096 + b * 1024 + unit,
                 ((unsigned)(t + 2) << 16) | (unsigned short)f2bf(h));
        dec_out[((size_t)(b * 128 + t)) * 1024 + unit] = h;
      }
      if (t < 127) xwv = *(const f32x4*)&sh.d.xws[bq * 128 + t + 1][q * 4];
    }
    return;
  }

  // ================= encoder LSTM role =================
  const int dir = bid >> 5, u0 = (bid & 31) * 16;
  const int unit = u0 + w * 4 + q;
  unsigned* hb = dir ? hb_b : hb_f;

  // publish h0 = 0 (tag 1, parity 0) early so peers' first polls can pass
  if (l15 < 4) st_coh(hb + l15 * 512 + unit, 1u << 16);

  const int colA = (l15 & 3) * 512 + u0 + w * 4 + (l15 >> 2);
  const float* Wx   = dir ? Wx_b : Wx_f;
  const float* bias = dir ? b_b : b_f;
  const float bcol = bias[colA];
  {
    bf16x8 bfr[16];
#pragma unroll
    for (int ks = 0; ks < 16; ++ks) {
      bf16x8 v;
#pragma unroll
      for (int jj = 0; jj < 8; ++jj)
        v[jj] = f2bf(Wx[(size_t)(ks * 32 + q * 8 + jj) * 2048 + colA]);
      bfr[ks] = v;
    }
    for (int mt = 0; mt < 32; ++mt) {
      f32x4 a0 = {0.f,0.f,0.f,0.f}, a1 = a0;
#pragma unroll
      for (int ks = 0; ks < 16; ks += 2) {
        bf16x8 f0 = *(const bf16x8*)(encx + ((size_t)(ks*4 + q) * 512 + mt*16 + l15) * 8);
        bf16x8 f1 = *(const bf16x8*)(encx + ((size_t)((ks+1)*4 + q) * 512 + mt*16 + l15) * 8);
        a0 = __builtin_amdgcn_mfma_f32_16x16x32_bf16(f0, bfr[ks], a0, 0, 0, 0);
        a1 = __builtin_amdgcn_mfma_f32_16x16x32_bf16(f1, bfr[ks+1], a1, 0, 0, 0);
      }
#pragma unroll
      for (int r = 0; r < 4; ++r) sh.e.xws[mt*16 + q*4 + r][l15] = a0[r] + a1[r] + bcol;
    }
  }
  const float* Wh = dir ? Wh_b : Wh_f;
  bf16x8 wfrag[16];
#pragma unroll
  for (int ks = 0; ks < 16; ++ks) {
    bf16x8 v;
#pragma unroll
    for (int jj = 0; jj < 8; ++jj)
      v[jj] = f2bf(Wh[(size_t)(ks * 32 + q * 8 + jj) * 2048 + colA]);
    wfrag[ks] = v;
  }
  __syncthreads();
  float creg = 0.f;
  f32x4 xwv = *(const f32x4*)&sh.e.xws[bq * 128 + (dir ? 127 : 0)][q * 4];

#pragma unroll 1
  for (int t = 0; t < 128; ++t) {
    const unsigned exp_ = (unsigned)(t + 1);
    const unsigned* src = hb + (t & 1) * 2048;
    unsigned pa[8], pb[8];
#pragma unroll
    for (int j = 0; j < 8; ++j) pa[j] = ld_coh(src + j * 256 + tid);
#pragma unroll
    for (int j = 0; j < 8; ++j) pb[j] = ld_coh(src + j * 256 + tid);
    int g = 0;
    for (;;) {
      bool ok = true;
#pragma unroll
      for (int j = 0; j < 8; ++j) ok &= (pa[j] >> 16) == exp_;
      if (ok || g > (1 << 20)) break;
      __builtin_amdgcn_s_sleep(1);
#pragma unroll
      for (int j = 0; j < 8; ++j) pa[j] = pb[j];
#pragma unroll
      for (int j = 0; j < 8; ++j) pb[j] = ld_coh(src + j * 256 + tid);
      ++g;
    }
#pragma unroll
    for (int j = 0; j < 8; ++j) {
      int idx = j * 256 + tid;
      sh.e.hs[idx >> 9][idx & 511] = (short)(pa[j] & 0xffffu);
    }
    __syncthreads();                     // the only barrier per step

    f32x4 a0 = {0.f,0.f,0.f,0.f}, a1 = a0, a2 = a0, a3 = a0;
    const short* hrow = sh.e.hs[bq];
#pragma unroll
    for (int ks = 0; ks < 16; ks += 4) {
      bf16x8 h0 = *(const bf16x8*)(hrow + ks * 32 + q * 8);
      bf16x8 h1 = *(const bf16x8*)(hrow + (ks+1) * 32 + q * 8);
      bf16x8 h2 = *(const bf16x8*)(hrow + (ks+2) * 32 + q * 8);
      bf16x8 h3 = *(const bf16x8*)(hrow + (ks+3) * 32 + q * 8);
      a0 = __builtin_amdgcn_mfma_f32_16x16x32_bf16(wfrag[ks],   h0, a0, 0, 0, 0);
      a1 = __builtin_amdgcn_mfma_f32_16x16x32_bf16(wfrag[ks+1], h1, a1, 0, 0, 0);
      a2 = __builtin_amdgcn_mfma_f32_16x16x32_bf16(wfrag[ks+2], h2, a2, 0, 0, 0);
      a3 = __builtin_amdgcn_mfma_f32_16x16x32_bf16(wfrag[ks+3], h3, a3, 0, 0, 0);
    }
    const int tx = dir ? (127 - t) : t;
    if (l15 < 4) {
      const int b = l15;
      float zi = a0[0] + a1[0] + a2[0] + a3[0] + xwv[0];
      float zf = a0[1] + a1[1] + a2[1] + a3[1] + xwv[1];
      float zg = a0[2] + a1[2] + a2[2] + a3[2] + xwv[2];
      float zo = a0[3] + a1[3] + a2[3] + a3[3] + xwv[3];
      float cst = sigf(zf) * creg + sigf(zi) * tanhf_fast(zg);
      creg = cst;
      float h = sigf(zo) * tanhf_fast(cst);
      if (t < 127)
        st_coh(hb + ((t + 1) & 1) * 2048 + b * 512 + unit,
               ((unsigned)(t + 2) << 16) | (unsigned short)f2bf(h));
      if (tx == 127)                     // hand dec its h0 half (tag 1)
        st_coh(hb_d + b * 1024 + dir * 512 + unit,
               (1u << 16) | (unsigned short)f2bf(h));
      const int d = dir * 512 + unit;
      enc_out[((size_t)(b * 128 + tx)) * 1024 + d] = h;
      encT[((size_t)(b * 1024 + d)) * 128 + tx] = h;
    }
    if (t < 127)
      xwv = *(const f32x4*)&sh.e.xws[bq * 128 + (dir ? 126 - t : t + 1)][q * 4];
  }
}

// ---- attention: one block per (b,t); writes swizzled bf16 attn ------------
__global__ __launch_bounds__(256) void attention(
    const float* __restrict__ dec_out, const float* __restrict__ enc_out,
    const float* __restrict__ encT, const float* __restrict__ scale,
    short* __restrict__ attn_swz) {
  const int m = blockIdx.x, b = m >> 7, tid = threadIdx.x;
  __shared__ float dec_s[1024], scl_s[1024];
  __shared__ float red[256], wts[128], sred[2];
  for (int d = tid; d < 1024; d += 256) {
    dec_s[d] = dec_out[(size_t)m * 1024 + d];
    scl_s[d] = scale[d];
  }
  __syncthreads();
  const int s = tid & 127, half = tid >> 7;
  float sc = 0.f;
  const float* ep = encT + (size_t)b * 1024 * 128 + s;
  for (int d = half * 512; d < half * 512 + 512; ++d)
    sc += tanhf_fast(dec_s[d] + ep[(size_t)d * 128]) * scl_s[d];
  red[tid] = sc;
  __syncthreads();
  float v = 0.f;
  if (tid < 128) { v = red[tid] + red[tid + 128]; wts[tid] = v; }
  __syncthreads();
  if (tid < 64) {
    float mx = fmaxf(wts[tid], wts[tid + 64]);
    for (int off = 32; off; off >>= 1) mx = fmaxf(mx, __shfl_down(mx, off));
    if (tid == 0) sred[0] = mx;
  }
  __syncthreads();
  const float MX = sred[0];
  if (tid < 128) { v = __expf(v - MX); wts[tid] = v; }
  __syncthreads();
  if (tid < 64) {
    float sm = wts[tid] + wts[tid + 64];
    for (int off = 32; off; off >>= 1) sm += __shfl_down(sm, off);
    if (tid == 0) sred[1] = sm;
  }
  __syncthreads();
  const float inv = 1.f / sred[1];
  if (tid < 128) wts[tid] = v * inv;
  __syncthreads();
#pragma unroll
  for (int kk = 0; kk < 4; ++kk) {
    int d = tid + kk * 256;
    float a = 0.f;
    for (int ss = 0; ss < 128; ++ss)
      a += wts[ss] * enc_out[((size_t)(b * 128 + ss)) * 1024 + d];
    attn_swz[((size_t)(d >> 3) * 512 + m) * 8 + (d & 7)] = f2bf(a);
  }
}

// ---- logits = attn @ Wo (LDS-free swizzled GEMM, bf16 out) ----------------
__global__ __launch_bounds__(256) void gemm_wo(const short* __restrict__ A,
                                               const short* __restrict__ B,
                                               short* __restrict__ Cb) {
  const int wv = threadIdx.x >> 6, lane = threadIdx.x & 63;
  const int q = lane >> 4, l15 = lane & 15;
  const int m0 = blockIdx.y * 128 + (wv >> 1) * 64;
  const int n0 = blockIdx.x * 128 + (wv & 1) * 64;
  const int M = 512, N = 32000;
  f32x4 acc[4][4];
#pragma unroll
  for (int i = 0; i < 4; ++i)
#pragma unroll
    for (int j = 0; j < 4; ++j) acc[i][j] = (f32x4){0.f, 0.f, 0.f, 0.f};
  for (int ks = 0; ks < 32; ++ks) {
    const size_t k8 = (size_t)(ks * 4 + q);
    const short* Ap = A + (k8 * M + m0 + l15) * 8;
    const short* Bp = B + (k8 * N + n0 + l15) * 8;
    bf16x8 av[4], bv[4];
#pragma unroll
    for (int i = 0; i < 4; ++i) av[i] = *(const bf16x8*)(Ap + i * 128);
#pragma unroll
    for (int j = 0; j < 4; ++j) bv[j] = *(const bf16x8*)(Bp + j * 128);
#pragma unroll
    for (int i = 0; i < 4; ++i)
#pragma unroll
      for (int j = 0; j < 4; ++j)
        acc[i][j] = __builtin_amdgcn_mfma_f32_16x16x32_bf16(av[i], bv[j], acc[i][j], 0, 0, 0);
  }
#pragma unroll
  for (int i = 0; i < 4; ++i)
#pragma unroll
    for (int j = 0; j < 4; ++j)
#pragma unroll
      for (int r = 0; r < 4; ++r)
        Cb[(size_t)(m0 + i * 16 + q * 4 + r) * N + (n0 + j * 16 + l15)] = f2bf(acc[i][j][r]);
}

// ---- row softmax over 32000 vocab, bf16 logits + bias -> fp32 probs -------
__global__ __launch_bounds__(256) void softmax_out(const short* __restrict__ logits,
                                                   const float* __restrict__ bo,
                                                   float* __restrict__ out) {
  const int m = blockIdx.x, tid = threadIdx.x;
  __shared__ float red[256];
  const short* lp = logits + (size_t)m * 32000;
  float mx = -1e30f;
  for (int n = tid; n < 32000; n += 256) mx = fmaxf(mx, b2f(lp[n]) + bo[n]);
  red[tid] = mx;
  __syncthreads();
  for (int s2 = 128; s2 > 0; s2 >>= 1) {
    if (tid < s2) red[tid] = fmaxf(red[tid], red[tid + s2]);
    __syncthreads();
  }
  const float M = red[0];
  __syncthreads();
  float sm = 0.f;
  for (int n = tid; n < 32000; n += 256) sm += __expf(b2f(lp[n]) + bo[n] - M);
  red[tid] = sm;
  __syncthreads();
  for (int s2 = 128; s2 > 0; s2 >>= 1) {
    if (tid < s2) red[tid] += red[tid + s2];
    __syncthreads();
  }
  const float inv = 1.f / red[0];
  for (int n = tid; n < 32000; n += 256)
    out[(size_t)m * 32000 + n] = __expf(b2f(lp[n]) + bo[n] - M) * inv;
}

// ---------------------------------------------------------------------------
extern "C" void kernel_launch(void* const* d_in, const int* in_sizes, int n_in,
                              void* d_out, int out_size, void* d_ws, size_t ws_size,
                              hipStream_t stream) {
  (void)in_sizes; (void)n_in; (void)out_size;
  if (ws_size < WS_NEED) return;

  const int*   input_seq  = (const int*)d_in[0];
  const int*   output_seq = (const int*)d_in[1];
  const float* enc_emb    = (const float*)d_in[2];
  const float* dec_emb    = (const float*)d_in[3];
  const float* Wx_f = (const float*)d_in[4];
  const float* Wh_f = (const float*)d_in[5];
  const float* b_f  = (const float*)d_in[6];
  const float* Wx_b = (const float*)d_in[7];
  const float* Wh_b = (const float*)d_in[8];
  const float* b_b  = (const float*)d_in[9];
  const float* Wx_d = (const float*)d_in[10];
  const float* Wh_d = (const float*)d_in[11];
  const float* b_d  = (const float*)d_in[12];
  const float* attn_scale = (const float*)d_in[13];
  const float* Wo   = (const float*)d_in[14];
  const float* bo   = (const float*)d_in[15];
  float* out = (float*)d_out;

  char* ws = (char*)d_ws;
  unsigned* hbf   = (unsigned*)(ws + OFF_HBF);
  unsigned* hbb   = (unsigned*)(ws + OFF_HBB);
  unsigned* hbd   = (unsigned*)(ws + OFF_HBD);
  float* dec_out  = (float*)(ws + OFF_DECO);
  short* encx     = (short*)(ws + OFF_ENCX);
  short* decx     = (short*)(ws + OFF_DECX);
  short* wo_s     = (short*)(ws + OFF_WOS);
  float* enc_out  = (float*)(ws + OFF_ENCO);
  float* encT     = (float*)(ws + OFF_ENCT);
  short* attn_s   = (short*)(ws + OFF_ATTN);
  short* logits   = (short*)(ws + OFF_LOG);

  // No memset: 0xAA poison yields tag 0xAAAA which never matches a valid tag.

  prep<<<256, 256, 0, stream>>>(input_seq, output_seq, enc_emb, dec_emb, encx, decx);
  lstm_mega<<<128 + 16000, 256, 0, stream>>>(
      Wh_f, Wh_b, Wx_f, Wx_b, b_f, b_b, Wh_d, Wx_d, b_d,
      encx, decx, hbf, hbb, hbd, enc_out, encT, dec_out, Wo, wo_s);
  attention<<<512, 256, 0, stream>>>(dec_out, enc_out, encT, attn_scale, attn_s);
  gemm_wo<<<dim3(250, 4), 256, 0, stream>>>(attn_s, wo_s, logits);
  softmax_out<<<512, 256, 0, stream>>>(logits, bo, out);
}